// Round 1
// baseline (654.395 us; speedup 1.0000x reference)
//
#include <hip/hip_runtime.h>
#include <stdint.h>

// ---------------------------------------------------------------------------
// QuantQwenMLP: W4A8 fake-quant SwiGLU MLP.
//   B=4 S=2048 H=2048 I=5632  -> M = B*S = 8192 tokens
// R3 -> R4: m97-structure (2 __syncthreads/K-step, vmcnt(0) drains) was the
// ceiling (34% of i8 peak, no pipe >45% busy). Rewrite both GEMMs into the
// m201-style pipelined template: BM=256xBN=128xBK=64, 512 thr, 4 LDS buffers
// (depth-3 prefetch), raw s_barrier + counted s_waitcnt vmcnt(8/4/0) so
// global_load_lds stays in flight across barriers, setprio(1) around MFMA
// clusters, bijective XCD swizzle.
// ---------------------------------------------------------------------------

typedef int i32x4  __attribute__((ext_vector_type(4)));
typedef int i32x16 __attribute__((ext_vector_type(16)));

#define BM 256
#define BN 128
#define BK 64       // bytes along K per LDS step
#define NBUF 4

#define WAITVM(N) asm volatile("s_waitcnt vmcnt(" #N ")" ::: "memory")
#define LGKM0()   asm volatile("s_waitcnt lgkmcnt(0)" ::: "memory")
#define BAR()     __builtin_amdgcn_s_barrier()
#define MFMA_I8   __builtin_amdgcn_mfma_i32_32x32x32_i8

__device__ __forceinline__ void load_lds16(const void* g, void* l) {
    __builtin_amdgcn_global_load_lds(
        (const __attribute__((address_space(1))) unsigned int*)g,
        (__attribute__((address_space(3))) unsigned int*)l,
        16, 0, 0);
}

// ---------------------------------------------------------------------------
// Per-row symmetric fake-quant: scale = max(amax/qmax, 1e-8); q = clip(rint(v/scale))
// One block per row; row cached in LDS so global is read once.
// ---------------------------------------------------------------------------
__global__ __launch_bounds__(256) void quant_rows(
    const float* __restrict__ src, int8_t* __restrict__ dst,
    float* __restrict__ scales, int C4, float qmax)
{
    __shared__ float4 buf[1408];        // up to 5632 floats = 22.5 KB
    __shared__ float wmax[4];
    const int r = blockIdx.x;
    const float4* s4 = (const float4*)src + (long)r * C4;

    float am = 0.f;
    for (int i = threadIdx.x; i < C4; i += 256) {
        float4 v = s4[i];
        buf[i] = v;
        am = fmaxf(am, fmaxf(fmaxf(fabsf(v.x), fabsf(v.y)),
                             fmaxf(fabsf(v.z), fabsf(v.w))));
    }
    #pragma unroll
    for (int off = 32; off; off >>= 1)
        am = fmaxf(am, __shfl_xor(am, off));
    if ((threadIdx.x & 63) == 0) wmax[threadIdx.x >> 6] = am;
    __syncthreads();
    const float amax = fmaxf(fmaxf(wmax[0], wmax[1]), fmaxf(wmax[2], wmax[3]));
    const float scale = fmaxf(amax / qmax, 1e-8f);
    if (threadIdx.x == 0) scales[r] = scale;

    char4* d4 = (char4*)dst + (long)r * C4;
    for (int i = threadIdx.x; i < C4; i += 256) {
        float4 v = buf[i];
        char4 q;
        q.x = (signed char)(int)fminf(fmaxf(rintf(v.x / scale), -qmax), qmax);
        q.y = (signed char)(int)fminf(fmaxf(rintf(v.y / scale), -qmax), qmax);
        q.z = (signed char)(int)fminf(fmaxf(rintf(v.z / scale), -qmax), qmax);
        q.w = (signed char)(int)fminf(fmaxf(rintf(v.w / scale), -qmax), qmax);
        d4[i] = q;
    }
}

// ---------------------------------------------------------------------------
// LDS tile layout (per buffer), BK=64 => 4 x 16B chunks per row.
// LDS slot (row, c) holds global K-chunk (c ^ ((row>>1)&3)): even/odd rows
// already alternate LDS bank halves at 64B pitch; XOR on (row>>1) spreads the
// 4 chunk slots so a 32-lane fragment read is the uniform 4-per-bank-group
// minimum. Stage side: linear LDS dest (global_load_lds requirement) +
// pre-swizzled GLOBAL source chunk -- same involution on both sides.
// Fragment read: row = rowbase + (lane&31); chunk q = ks*2 + (lane>>5);
// byte = row*64 + ((q ^ ((cl>>1)&3))<<4).
// ---------------------------------------------------------------------------

// ---------------------------------------------------------------------------
// Fused gate+up int8 GEMM with SwiGLU epilogue (fp32 H out).
// Pipelined: 4 buffers, prefetch depth 3, counted vmcnt, 2 phases/K-step.
// ---------------------------------------------------------------------------
__global__ __launch_bounds__(512, 2) void gemm_dual(
    const int8_t* __restrict__ Aq, const float* __restrict__ sA,
    const int8_t* __restrict__ Bg, const float* __restrict__ sBg,
    const int8_t* __restrict__ Bu, const float* __restrict__ sBu,
    float* __restrict__ H, int M, int N, int K)
{
    __shared__ int8_t lds[NBUF][BM*BK + 2*BN*BK];   // 4 x 32 KB = 128 KB

    const int tid  = threadIdx.x;
    const int lane = tid & 63;
    const int cl   = lane & 31;
    const int kq   = lane >> 5;
    const int wave = tid >> 6;
    const int wm   = (wave >> 1) * 64;    // 4 M-waves
    const int wn   = (wave & 1) * 64;     // 2 N-waves

    // bijective XCD swizzle (grids here are all %8==0)
    int bx = blockIdx.x, by = blockIdx.y;
    {
        const int nwg = gridDim.x * gridDim.y;
        if ((nwg & 7) == 0) {
            int bid = by * gridDim.x + bx;
            int s = (bid & 7) * (nwg >> 3) + (bid >> 3);
            bx = s % gridDim.x;
            by = s / gridDim.x;
        }
    }
    const long m0 = (long)by * BM;
    const long n0 = (long)bx * BN;

    // ---- stage source pointers: thread owns A chunks {tid, tid+512}, G/U chunk tid
    const int r0 = tid >> 2;                         // 0..127
    const int c0 = (tid & 3) ^ ((tid >> 3) & 3);     // swizzled source chunk
    const int8_t* pA0 = Aq + (m0 + r0)       * (long)K + c0 * 16;
    const int8_t* pA1 = Aq + (m0 + r0 + 128) * (long)K + c0 * 16;
    const int8_t* pG  = Bg + (n0 + r0)       * (long)K + c0 * 16;
    const int8_t* pU  = Bu + (n0 + r0)       * (long)K + c0 * 16;
    const int dA0 = tid * 16;
    const int dA1 = tid * 16 + BM*BK/2;
    const int dG  = BM*BK + tid * 16;
    const int dU  = BM*BK + BN*BK + tid * 16;

    // ---- fragment read offsets
    const int swz = (cl >> 1) & 3;
    const int s0b = ((0 + kq) ^ swz) * 16;   // ks=0
    const int s1b = ((2 + kq) ^ swz) * 16;   // ks=1
    const int rAa = (wm      + cl) * BK;
    const int rAb = (wm + 32 + cl) * BK;
    const int rBa = (wn      + cl) * BK;
    const int rBb = (wn + 32 + cl) * BK;

    i32x16 accg[2][2], accu[2][2];
    #pragma unroll
    for (int i = 0; i < 2; ++i)
        #pragma unroll
        for (int j = 0; j < 2; ++j) {
            accg[i][j] = i32x16{0,0,0,0,0,0,0,0,0,0,0,0,0,0,0,0};
            accu[i][j] = i32x16{0,0,0,0,0,0,0,0,0,0,0,0,0,0,0,0};
        }

    const int NT = K / BK;   // 32 (K=2048), always >= 4 here

    // prologue: stage steps 0..2 (12 loads in flight), wait for step 0 only
    #pragma unroll
    for (int t = 0; t < 3; ++t) {
        const int kk = t * BK;
        load_lds16(pA0 + kk, &lds[t][dA0]);
        load_lds16(pG  + kk, &lds[t][dG]);
        load_lds16(pA1 + kk, &lds[t][dA1]);
        load_lds16(pU  + kk, &lds[t][dU]);
    }
    WAITVM(8);
    BAR();

    for (int t = 0; t < NT; ++t) {
        const int8_t* cb  = lds[t & 3];
        const int8_t* cbG = cb + BM*BK;
        const int8_t* cbU = cb + BM*BK + BN*BK;
        int8_t* nb = lds[(t + 3) & 3];
        const int kk = (t + 3) * BK;
        const bool pf = (t + 3) < NT;

        // -------- phase 0 : ks=0 --------
        if (pf) {
            load_lds16(pA0 + kk, nb + dA0);
            load_lds16(pG  + kk, nb + dG);
        }
        i32x4 a0 = *(const i32x4*)(cb  + rAa + s0b);
        i32x4 a1 = *(const i32x4*)(cb  + rAb + s0b);
        i32x4 g0 = *(const i32x4*)(cbG + rBa + s0b);
        i32x4 g1 = *(const i32x4*)(cbG + rBb + s0b);
        i32x4 u0 = *(const i32x4*)(cbU + rBa + s0b);
        i32x4 u1 = *(const i32x4*)(cbU + rBb + s0b);
        BAR();
        LGKM0();                        // all reads retired before MFMA cluster
        __builtin_amdgcn_s_setprio(1);
        accg[0][0] = MFMA_I8(a0, g0, accg[0][0], 0, 0, 0);
        accg[0][1] = MFMA_I8(a0, g1, accg[0][1], 0, 0, 0);
        accg[1][0] = MFMA_I8(a1, g0, accg[1][0], 0, 0, 0);
        accg[1][1] = MFMA_I8(a1, g1, accg[1][1], 0, 0, 0);
        accu[0][0] = MFMA_I8(a0, u0, accu[0][0], 0, 0, 0);
        accu[0][1] = MFMA_I8(a0, u1, accu[0][1], 0, 0, 0);
        accu[1][0] = MFMA_I8(a1, u0, accu[1][0], 0, 0, 0);
        accu[1][1] = MFMA_I8(a1, u1, accu[1][1], 0, 0, 0);
        __builtin_amdgcn_s_setprio(0);
        BAR();

        // -------- phase 1 : ks=1 --------
        if (pf) {
            load_lds16(pA1 + kk, nb + dA1);
            load_lds16(pU  + kk, nb + dU);
        }
        a0 = *(const i32x4*)(cb  + rAa + s1b);
        a1 = *(const i32x4*)(cb  + rAb + s1b);
        g0 = *(const i32x4*)(cbG + rBa + s1b);
        g1 = *(const i32x4*)(cbG + rBb + s1b);
        u0 = *(const i32x4*)(cbU + rBa + s1b);
        u1 = *(const i32x4*)(cbU + rBb + s1b);
        BAR();
        LGKM0();
        __builtin_amdgcn_s_setprio(1);
        accg[0][0] = MFMA_I8(a0, g0, accg[0][0], 0, 0, 0);
        accg[0][1] = MFMA_I8(a0, g1, accg[0][1], 0, 0, 0);
        accg[1][0] = MFMA_I8(a1, g0, accg[1][0], 0, 0, 0);
        accg[1][1] = MFMA_I8(a1, g1, accg[1][1], 0, 0, 0);
        accu[0][0] = MFMA_I8(a0, u0, accu[0][0], 0, 0, 0);
        accu[0][1] = MFMA_I8(a0, u1, accu[0][1], 0, 0, 0);
        accu[1][0] = MFMA_I8(a1, u0, accu[1][0], 0, 0, 0);
        accu[1][1] = MFMA_I8(a1, u1, accu[1][1], 0, 0, 0);
        __builtin_amdgcn_s_setprio(0);

        // counted vmcnt: only retire next step's 4 loads; never drain to 0
        // while the pipeline is full. Steady in-flight = 12.
        const int ahead = NT - 1 - t;
        if (ahead >= 3)      WAITVM(8);
        else if (ahead == 2) WAITVM(4);
        else if (ahead == 1) WAITVM(0);
        BAR();
    }

    // Epilogue. 32x32 C/D layout: col = lane&31, row = (reg&3)+8*(reg>>2)+4*(lane>>5).
    float sg[2], su[2];
    #pragma unroll
    for (int ni = 0; ni < 2; ++ni) {
        long n = n0 + wn + ni * 32 + cl;
        sg[ni] = sBg[n];
        su[ni] = sBu[n];
    }
    #pragma unroll
    for (int mi = 0; mi < 2; ++mi) {
        #pragma unroll
        for (int reg = 0; reg < 16; ++reg) {
            long m = m0 + wm + mi * 32 + (reg & 3) + 8 * (reg >> 2) + 4 * kq;
            float sa = sA[m];
            #pragma unroll
            for (int ni = 0; ni < 2; ++ni) {
                long n = n0 + wn + ni * 32 + cl;
                float g = (float)accg[mi][ni][reg] * sa * sg[ni];
                float u = (float)accu[mi][ni][reg] * sa * su[ni];
                float s = 1.f / (1.f + expf(-g));
                H[m * N + n] = (g * s) * u;
            }
        }
    }
}

// ---------------------------------------------------------------------------
// Single int8 GEMM: out[m][n] = acc * sA[m] * sB[n].  Same pipeline,
// 3 loads/step -> waits vmcnt(6/3/0).
// ---------------------------------------------------------------------------
__global__ __launch_bounds__(512, 2) void gemm_single(
    const int8_t* __restrict__ Aq, const float* __restrict__ sA,
    const int8_t* __restrict__ Bq, const float* __restrict__ sB,
    float* __restrict__ O, int M, int N, int K)
{
    __shared__ int8_t lds[NBUF][BM*BK + BN*BK];     // 4 x 24 KB = 96 KB

    const int tid  = threadIdx.x;
    const int lane = tid & 63;
    const int cl   = lane & 31;
    const int kq   = lane >> 5;
    const int wave = tid >> 6;
    const int wm   = (wave >> 1) * 64;
    const int wn   = (wave & 1) * 64;

    int bx = blockIdx.x, by = blockIdx.y;
    {
        const int nwg = gridDim.x * gridDim.y;
        if ((nwg & 7) == 0) {
            int bid = by * gridDim.x + bx;
            int s = (bid & 7) * (nwg >> 3) + (bid >> 3);
            bx = s % gridDim.x;
            by = s / gridDim.x;
        }
    }
    const long m0 = (long)by * BM;
    const long n0 = (long)bx * BN;

    const int r0 = tid >> 2;
    const int c0 = (tid & 3) ^ ((tid >> 3) & 3);
    const int8_t* pA0 = Aq + (m0 + r0)       * (long)K + c0 * 16;
    const int8_t* pA1 = Aq + (m0 + r0 + 128) * (long)K + c0 * 16;
    const int8_t* pB  = Bq + (n0 + r0)       * (long)K + c0 * 16;
    const int dA0 = tid * 16;
    const int dA1 = tid * 16 + BM*BK/2;
    const int dB  = BM*BK + tid * 16;

    const int swz = (cl >> 1) & 3;
    const int s0b = ((0 + kq) ^ swz) * 16;
    const int s1b = ((2 + kq) ^ swz) * 16;
    const int rAa = (wm      + cl) * BK;
    const int rAb = (wm + 32 + cl) * BK;
    const int rBa = (wn      + cl) * BK;
    const int rBb = (wn + 32 + cl) * BK;

    i32x16 acc[2][2];
    #pragma unroll
    for (int i = 0; i < 2; ++i)
        #pragma unroll
        for (int j = 0; j < 2; ++j)
            acc[i][j] = i32x16{0,0,0,0,0,0,0,0,0,0,0,0,0,0,0,0};

    const int NT = K / BK;   // 88 (K=5632)

    #pragma unroll
    for (int t = 0; t < 3; ++t) {
        const int kk = t * BK;
        load_lds16(pA0 + kk, &lds[t][dA0]);
        load_lds16(pB  + kk, &lds[t][dB]);
        load_lds16(pA1 + kk, &lds[t][dA1]);
    }
    WAITVM(6);
    BAR();

    for (int t = 0; t < NT; ++t) {
        const int8_t* cb  = lds[t & 3];
        const int8_t* cbB = cb + BM*BK;
        int8_t* nb = lds[(t + 3) & 3];
        const int kk = (t + 3) * BK;
        const bool pf = (t + 3) < NT;

        // -------- phase 0 : ks=0 --------
        if (pf) {
            load_lds16(pA0 + kk, nb + dA0);
            load_lds16(pB  + kk, nb + dB);
        }
        i32x4 a0 = *(const i32x4*)(cb  + rAa + s0b);
        i32x4 a1 = *(const i32x4*)(cb  + rAb + s0b);
        i32x4 b0 = *(const i32x4*)(cbB + rBa + s0b);
        i32x4 b1 = *(const i32x4*)(cbB + rBb + s0b);
        BAR();
        LGKM0();
        __builtin_amdgcn_s_setprio(1);
        acc[0][0] = MFMA_I8(a0, b0, acc[0][0], 0, 0, 0);
        acc[0][1] = MFMA_I8(a0, b1, acc[0][1], 0, 0, 0);
        acc[1][0] = MFMA_I8(a1, b0, acc[1][0], 0, 0, 0);
        acc[1][1] = MFMA_I8(a1, b1, acc[1][1], 0, 0, 0);
        __builtin_amdgcn_s_setprio(0);
        BAR();

        // -------- phase 1 : ks=1 --------
        if (pf) {
            load_lds16(pA1 + kk, nb + dA1);
        }
        a0 = *(const i32x4*)(cb  + rAa + s1b);
        a1 = *(const i32x4*)(cb  + rAb + s1b);
        b0 = *(const i32x4*)(cbB + rBa + s1b);
        b1 = *(const i32x4*)(cbB + rBb + s1b);
        BAR();
        LGKM0();
        __builtin_amdgcn_s_setprio(1);
        acc[0][0] = MFMA_I8(a0, b0, acc[0][0], 0, 0, 0);
        acc[0][1] = MFMA_I8(a0, b1, acc[0][1], 0, 0, 0);
        acc[1][0] = MFMA_I8(a1, b0, acc[1][0], 0, 0, 0);
        acc[1][1] = MFMA_I8(a1, b1, acc[1][1], 0, 0, 0);
        __builtin_amdgcn_s_setprio(0);

        const int ahead = NT - 1 - t;
        if (ahead >= 3)      WAITVM(6);
        else if (ahead == 2) WAITVM(3);
        else if (ahead == 1) WAITVM(0);
        BAR();
    }

    float sb[2];
    #pragma unroll
    for (int ni = 0; ni < 2; ++ni) sb[ni] = sB[n0 + wn + ni * 32 + cl];
    #pragma unroll
    for (int mi = 0; mi < 2; ++mi) {
        #pragma unroll
        for (int reg = 0; reg < 16; ++reg) {
            long m = m0 + wm + mi * 32 + (reg & 3) + 8 * (reg >> 2) + 4 * kq;
            float sa = sA[m];
            #pragma unroll
            for (int ni = 0; ni < 2; ++ni) {
                long n = n0 + wn + ni * 32 + cl;
                O[m * N + n] = (float)acc[mi][ni][reg] * sa * sb[ni];
            }
        }
    }
}

// ---------------------------------------------------------------------------

extern "C" void kernel_launch(void* const* d_in, const int* in_sizes, int n_in,
                              void* d_out, int out_size, void* d_ws, size_t ws_size,
                              hipStream_t stream)
{
    const float* x  = (const float*)d_in[0];   // [4,2048,2048]
    const float* Wg = (const float*)d_in[1];   // [5632,2048]
    const float* Wu = (const float*)d_in[2];   // [5632,2048]
    const float* Wd = (const float*)d_in[3];   // [2048,5632]
    float* out = (float*)d_out;                // [4,2048,2048] fp32

    const int M  = 8192;      // B*S
    const int H  = 2048;
    const int I  = 5632;

    // ---- fixed workspace regions (~49.1 MiB) ----
    char* p = (char*)d_ws;
    int8_t* xq  = (int8_t*)p; p += (size_t)M * H;
    float*  sx  = (float*)p;  p += (size_t)M * 4;
    int8_t* wgq = (int8_t*)p; p += (size_t)I * H;
    float*  swg = (float*)p;  p += (size_t)I * 4;
    int8_t* wuq = (int8_t*)p; p += (size_t)I * H;
    float*  swu = (float*)p;  p += (size_t)I * 4;
    int8_t* wdq = (int8_t*)p; p += (size_t)H * I;
    float*  swd = (float*)p;  p += (size_t)H * 4;
    float*  sh  = (float*)p;  p += (size_t)M * 4;
    const size_t fixed_bytes = (size_t)(p - (char*)d_ws);

    // ---- largest M-chunk whose h (fp32) + hq (int8) fit ws_size ----
    int Mc = 256;
    for (int cand = 8192; cand >= 256; cand >>= 1) {
        size_t need = fixed_bytes + (size_t)cand * I * 5;
        if (need <= ws_size) { Mc = cand; break; }
    }
    float*  hbuf = (float*)p;  p += (size_t)Mc * I * 4;
    int8_t* hq   = (int8_t*)p;

    // 1) quantize weights (qmax=7) and activations (qmax=127)
    quant_rows<<<I, 256, 0, stream>>>(Wg, wgq, swg, H / 4, 7.f);
    quant_rows<<<I, 256, 0, stream>>>(Wu, wuq, swu, H / 4, 7.f);
    quant_rows<<<H, 256, 0, stream>>>(Wd, wdq, swd, I / 4, 7.f);
    quant_rows<<<M, 256, 0, stream>>>(x,  xq,  sx,  H / 4, 127.f);

    // 2) per M-chunk: gate+up GEMM + SwiGLU -> h ; quantize h ; down-proj
    for (int m0 = 0; m0 < M; m0 += Mc) {
        gemm_dual<<<dim3(I / BN, Mc / BM), 512, 0, stream>>>(
            xq + (size_t)m0 * H, sx + m0, wgq, swg, wuq, swu,
            hbuf, Mc, I, H);
        quant_rows<<<Mc, 256, 0, stream>>>(hbuf, hq, sh + m0, I / 4, 127.f);
        gemm_single<<<dim3(H / BN, Mc / BM), 512, 0, stream>>>(
            hq, sh + m0, wdq, swd, out + (size_t)m0 * H, Mc, H, I);
    }
}

// Round 3
// 651.259 us; speedup vs baseline: 1.0048x; 1.0048x over previous
//
#include <hip/hip_runtime.h>
#include <stdint.h>

// ---------------------------------------------------------------------------
// QuantQwenMLP: W4A8 fake-quant SwiGLU MLP.
//   B=4 S=2048 H=2048 I=5632  -> M = B*S = 8192 tokens
// R5 resubmit (container infra failure, no kernel verdict last round).
// LDS staging architecture was the bottleneck class (ds_read_b128 pipe
// ~12cyc/instr inherent + double data movement + barrier drains; the 8.65M
// "bank conflict" count is the b128 issue-slot cost, identical across
// swizzles). AITER-flatmm style: quantizers emit int8 in FRAGMENT-MAJOR
// layout, so each MFMA operand fragment is one contiguous 1024-B wave load
// (global_load_dwordx4) straight from L2/L3. No LDS, no barriers in the
// GEMMs. Column-band XCD swizzle keeps each XCD's weight panel (~3 MB)
// resident in its private 4 MB L2.
//
// Flat layout for int8 matrix [R][C] (C % 32 == 0), 16-B chunks:
//   chunk(r, c16) -> byte ((r>>5)*(C>>5) + (c16>>1))*1024
//                    + (((c16&1)<<5) | (r&31))*16
// A wave's fragment (row-group g, k-step ks): lane l reads
//   row = g*32 + (l&31), chunk c16 = 2*ks + (l>>5)
// which is exactly the contiguous block ((g*(C>>5)+ks)<<10) + l*16.
// ---------------------------------------------------------------------------

typedef int i32x4  __attribute__((ext_vector_type(4)));
typedef int i32x16 __attribute__((ext_vector_type(16)));

#define MFMA_I8 __builtin_amdgcn_mfma_i32_32x32x32_i8

__device__ __forceinline__ int pack4(float4 v, float scale, float qmax) {
    int a = (int)fminf(fmaxf(rintf(v.x / scale), -qmax), qmax);
    int b = (int)fminf(fmaxf(rintf(v.y / scale), -qmax), qmax);
    int c = (int)fminf(fmaxf(rintf(v.z / scale), -qmax), qmax);
    int d = (int)fminf(fmaxf(rintf(v.w / scale), -qmax), qmax);
    return (a & 255) | ((b & 255) << 8) | ((c & 255) << 16) | (d << 24);
}

// ---------------------------------------------------------------------------
// Per-row symmetric fake-quant writing the flat fragment-major layout.
// scale = max(amax/qmax, 1e-8); q = clip(rint(v/scale)). One block per row.
// ---------------------------------------------------------------------------
__global__ __launch_bounds__(256) void quant_rows_shuf(
    const float* __restrict__ src, int8_t* __restrict__ dst,
    float* __restrict__ scales, int C4, float qmax)
{
    __shared__ float4 buf[1408];        // up to 5632 floats = 22.5 KB
    __shared__ float wmax[4];
    const int r = blockIdx.x;
    const float4* s4 = (const float4*)src + (long)r * C4;

    float am = 0.f;
    for (int i = threadIdx.x; i < C4; i += 256) {
        float4 v = s4[i];
        buf[i] = v;
        am = fmaxf(am, fmaxf(fmaxf(fabsf(v.x), fabsf(v.y)),
                             fmaxf(fabsf(v.z), fabsf(v.w))));
    }
    #pragma unroll
    for (int off = 32; off; off >>= 1)
        am = fmaxf(am, __shfl_xor(am, off));
    if ((threadIdx.x & 63) == 0) wmax[threadIdx.x >> 6] = am;
    __syncthreads();
    const float amax = fmaxf(fmaxf(wmax[0], wmax[1]), fmaxf(wmax[2], wmax[3]));
    const float scale = fmaxf(amax / qmax, 1e-8f);
    if (threadIdx.x == 0) scales[r] = scale;

    const int C16 = C4 >> 2;            // 16-B chunks per row
    const int KC  = C4 >> 3;            // 32-B k-steps per row (C>>5)
    const int g   = r >> 5;
    const int rl  = r & 31;
    for (int i = threadIdx.x; i < C16; i += 256) {
        float4 v0 = buf[4*i+0], v1 = buf[4*i+1];
        float4 v2 = buf[4*i+2], v3 = buf[4*i+3];
        i32x4 q;
        q[0] = pack4(v0, scale, qmax);
        q[1] = pack4(v1, scale, qmax);
        q[2] = pack4(v2, scale, qmax);
        q[3] = pack4(v3, scale, qmax);
        size_t off = ((size_t)(g * KC + (i >> 1)) << 10)
                   + ((size_t)((((i & 1) << 5) | rl)) << 4);
        *(i32x4*)(dst + off) = q;
    }
}

// ---------------------------------------------------------------------------
// Fused gate+up int8 GEMM with SwiGLU epilogue (fp32 H out).
// Flat (no-LDS) main loop: 6 contiguous 1024-B wave loads + 16 MFMA per
// 2 k-steps, depth-2 register prefetch, zero barriers.
// ---------------------------------------------------------------------------
__global__ __launch_bounds__(256, 2) void gemm_dual_flat(
    const int8_t* __restrict__ Ash, const float* __restrict__ sA,
    const int8_t* __restrict__ Gsh, const float* __restrict__ sBg,
    const int8_t* __restrict__ Ush, const float* __restrict__ sBu,
    float* __restrict__ H, int M, int N, int K)
{
    const int KC   = K >> 5;            // 64 for K=2048
    const int tid  = threadIdx.x;
    const int lane = tid & 63;
    const int cl   = lane & 31;
    const int kq   = lane >> 5;
    const int wave = tid >> 6;
    const int wm   = (wave >> 1) * 64;
    const int wn   = (wave & 1) * 64;

    // column-band XCD swizzle: XCD j owns a contiguous bx band, iterates by.
    int bx, by;
    {
        const int nwg = gridDim.x * gridDim.y;
        int w = blockIdx.y * gridDim.x + blockIdx.x;
        int t = ((nwg & 7) == 0) ? ((w & 7) * (nwg >> 3) + (w >> 3)) : w;
        bx = t / gridDim.y;
        by = t - bx * gridDim.y;
    }
    const long m0 = (long)by * 128;
    const long n0 = (long)bx * 128;

    const size_t KB = (size_t)KC << 10;     // bytes per 32-row group
    const int8_t* pa0 = Ash + (size_t)((m0 + wm) >> 5) * KB + lane * 16;
    const int8_t* pa1 = pa0 + KB;
    const int8_t* pg0 = Gsh + (size_t)((n0 + wn) >> 5) * KB + lane * 16;
    const int8_t* pg1 = pg0 + KB;
    const int8_t* pu0 = Ush + (size_t)((n0 + wn) >> 5) * KB + lane * 16;
    const int8_t* pu1 = pu0 + KB;

    i32x16 accg[2][2], accu[2][2];
    #pragma unroll
    for (int i = 0; i < 2; ++i)
        #pragma unroll
        for (int j = 0; j < 2; ++j) {
            accg[i][j] = i32x16{0,0,0,0,0,0,0,0,0,0,0,0,0,0,0,0};
            accu[i][j] = i32x16{0,0,0,0,0,0,0,0,0,0,0,0,0,0,0,0};
        }

#define LDF(p, o) (*(const i32x4*)((p) + (o)))

    // preload k-steps 0 and 1
    i32x4 fa0 = LDF(pa0, 0),    fa1 = LDF(pa1, 0);
    i32x4 fg0 = LDF(pg0, 0),    fg1 = LDF(pg1, 0);
    i32x4 fu0 = LDF(pu0, 0),    fu1 = LDF(pu1, 0);
    i32x4 ha0 = LDF(pa0, 1024), ha1 = LDF(pa1, 1024);
    i32x4 hg0 = LDF(pg0, 1024), hg1 = LDF(pg1, 1024);
    i32x4 hu0 = LDF(pu0, 1024), hu1 = LDF(pu1, 1024);

    for (int ks = 0; ks < KC - 2; ks += 2) {
        // prefetch ks+2
        i32x4 na0 = LDF(pa0, 2048), na1 = LDF(pa1, 2048);
        i32x4 ng0 = LDF(pg0, 2048), ng1 = LDF(pg1, 2048);
        i32x4 nu0 = LDF(pu0, 2048), nu1 = LDF(pu1, 2048);
        accg[0][0] = MFMA_I8(fa0, fg0, accg[0][0], 0, 0, 0);
        accg[0][1] = MFMA_I8(fa0, fg1, accg[0][1], 0, 0, 0);
        accg[1][0] = MFMA_I8(fa1, fg0, accg[1][0], 0, 0, 0);
        accg[1][1] = MFMA_I8(fa1, fg1, accg[1][1], 0, 0, 0);
        accu[0][0] = MFMA_I8(fa0, fu0, accu[0][0], 0, 0, 0);
        accu[0][1] = MFMA_I8(fa0, fu1, accu[0][1], 0, 0, 0);
        accu[1][0] = MFMA_I8(fa1, fu0, accu[1][0], 0, 0, 0);
        accu[1][1] = MFMA_I8(fa1, fu1, accu[1][1], 0, 0, 0);
        // prefetch ks+3
        i32x4 ma0 = LDF(pa0, 3072), ma1 = LDF(pa1, 3072);
        i32x4 mg0 = LDF(pg0, 3072), mg1 = LDF(pg1, 3072);
        i32x4 mu0 = LDF(pu0, 3072), mu1 = LDF(pu1, 3072);
        accg[0][0] = MFMA_I8(ha0, hg0, accg[0][0], 0, 0, 0);
        accg[0][1] = MFMA_I8(ha0, hg1, accg[0][1], 0, 0, 0);
        accg[1][0] = MFMA_I8(ha1, hg0, accg[1][0], 0, 0, 0);
        accg[1][1] = MFMA_I8(ha1, hg1, accg[1][1], 0, 0, 0);
        accu[0][0] = MFMA_I8(ha0, hu0, accu[0][0], 0, 0, 0);
        accu[0][1] = MFMA_I8(ha0, hu1, accu[0][1], 0, 0, 0);
        accu[1][0] = MFMA_I8(ha1, hu0, accu[1][0], 0, 0, 0);
        accu[1][1] = MFMA_I8(ha1, hu1, accu[1][1], 0, 0, 0);
        fa0 = na0; fa1 = na1; fg0 = ng0; fg1 = ng1; fu0 = nu0; fu1 = nu1;
        ha0 = ma0; ha1 = ma1; hg0 = mg0; hg1 = mg1; hu0 = mu0; hu1 = mu1;
        pa0 += 2048; pa1 += 2048; pg0 += 2048; pg1 += 2048;
        pu0 += 2048; pu1 += 2048;
    }
    // tail: k-steps KC-2 and KC-1 (already in f/h sets)
    accg[0][0] = MFMA_I8(fa0, fg0, accg[0][0], 0, 0, 0);
    accg[0][1] = MFMA_I8(fa0, fg1, accg[0][1], 0, 0, 0);
    accg[1][0] = MFMA_I8(fa1, fg0, accg[1][0], 0, 0, 0);
    accg[1][1] = MFMA_I8(fa1, fg1, accg[1][1], 0, 0, 0);
    accu[0][0] = MFMA_I8(fa0, fu0, accu[0][0], 0, 0, 0);
    accu[0][1] = MFMA_I8(fa0, fu1, accu[0][1], 0, 0, 0);
    accu[1][0] = MFMA_I8(fa1, fu0, accu[1][0], 0, 0, 0);
    accu[1][1] = MFMA_I8(fa1, fu1, accu[1][1], 0, 0, 0);
    accg[0][0] = MFMA_I8(ha0, hg0, accg[0][0], 0, 0, 0);
    accg[0][1] = MFMA_I8(ha0, hg1, accg[0][1], 0, 0, 0);
    accg[1][0] = MFMA_I8(ha1, hg0, accg[1][0], 0, 0, 0);
    accg[1][1] = MFMA_I8(ha1, hg1, accg[1][1], 0, 0, 0);
    accu[0][0] = MFMA_I8(ha0, hu0, accu[0][0], 0, 0, 0);
    accu[0][1] = MFMA_I8(ha0, hu1, accu[0][1], 0, 0, 0);
    accu[1][0] = MFMA_I8(ha1, hu0, accu[1][0], 0, 0, 0);
    accu[1][1] = MFMA_I8(ha1, hu1, accu[1][1], 0, 0, 0);

    // Epilogue. 32x32 C/D layout: col = lane&31, row = (reg&3)+8*(reg>>2)+4*(lane>>5).
    float sg[2], su[2];
    #pragma unroll
    for (int ni = 0; ni < 2; ++ni) {
        long n = n0 + wn + ni * 32 + cl;
        sg[ni] = sBg[n];
        su[ni] = sBu[n];
    }
    #pragma unroll
    for (int mi = 0; mi < 2; ++mi) {
        #pragma unroll
        for (int reg = 0; reg < 16; ++reg) {
            long m = m0 + wm + mi * 32 + (reg & 3) + 8 * (reg >> 2) + 4 * kq;
            float sa = sA[m];
            #pragma unroll
            for (int ni = 0; ni < 2; ++ni) {
                long n = n0 + wn + ni * 32 + cl;
                float g = (float)accg[mi][ni][reg] * sa * sg[ni];
                float u = (float)accu[mi][ni][reg] * sa * su[ni];
                float s = 1.f / (1.f + expf(-g));
                H[m * N + n] = (g * s) * u;
            }
        }
    }
}

// ---------------------------------------------------------------------------
// Single int8 GEMM, flat: out[m][n] = acc * sA[m] * sB[n].
// ---------------------------------------------------------------------------
__global__ __launch_bounds__(256, 2) void gemm_single_flat(
    const int8_t* __restrict__ Ash, const float* __restrict__ sA,
    const int8_t* __restrict__ Bsh, const float* __restrict__ sB,
    float* __restrict__ O, int M, int N, int K)
{
    const int KC   = K >> 5;            // 176 for K=5632
    const int tid  = threadIdx.x;
    const int lane = tid & 63;
    const int cl   = lane & 31;
    const int kq   = lane >> 5;
    const int wave = tid >> 6;
    const int wm   = (wave >> 1) * 64;
    const int wn   = (wave & 1) * 64;

    int bx, by;
    {
        const int nwg = gridDim.x * gridDim.y;
        int w = blockIdx.y * gridDim.x + blockIdx.x;
        int t = ((nwg & 7) == 0) ? ((w & 7) * (nwg >> 3) + (w >> 3)) : w;
        bx = t / gridDim.y;
        by = t - bx * gridDim.y;
    }
    const long m0 = (long)by * 128;
    const long n0 = (long)bx * 128;

    const size_t KB = (size_t)KC << 10;
    const int8_t* pa0 = Ash + (size_t)((m0 + wm) >> 5) * KB + lane * 16;
    const int8_t* pa1 = pa0 + KB;
    const int8_t* pb0 = Bsh + (size_t)((n0 + wn) >> 5) * KB + lane * 16;
    const int8_t* pb1 = pb0 + KB;

    i32x16 acc[2][2];
    #pragma unroll
    for (int i = 0; i < 2; ++i)
        #pragma unroll
        for (int j = 0; j < 2; ++j)
            acc[i][j] = i32x16{0,0,0,0,0,0,0,0,0,0,0,0,0,0,0,0};

    i32x4 fa0 = LDF(pa0, 0),    fa1 = LDF(pa1, 0);
    i32x4 fb0 = LDF(pb0, 0),    fb1 = LDF(pb1, 0);
    i32x4 ha0 = LDF(pa0, 1024), ha1 = LDF(pa1, 1024);
    i32x4 hb0 = LDF(pb0, 1024), hb1 = LDF(pb1, 1024);

    for (int ks = 0; ks < KC - 2; ks += 2) {
        i32x4 na0 = LDF(pa0, 2048), na1 = LDF(pa1, 2048);
        i32x4 nb0 = LDF(pb0, 2048), nb1 = LDF(pb1, 2048);
        acc[0][0] = MFMA_I8(fa0, fb0, acc[0][0], 0, 0, 0);
        acc[0][1] = MFMA_I8(fa0, fb1, acc[0][1], 0, 0, 0);
        acc[1][0] = MFMA_I8(fa1, fb0, acc[1][0], 0, 0, 0);
        acc[1][1] = MFMA_I8(fa1, fb1, acc[1][1], 0, 0, 0);
        i32x4 ma0 = LDF(pa0, 3072), ma1 = LDF(pa1, 3072);
        i32x4 mb0 = LDF(pb0, 3072), mb1 = LDF(pb1, 3072);
        acc[0][0] = MFMA_I8(ha0, hb0, acc[0][0], 0, 0, 0);
        acc[0][1] = MFMA_I8(ha0, hb1, acc[0][1], 0, 0, 0);
        acc[1][0] = MFMA_I8(ha1, hb0, acc[1][0], 0, 0, 0);
        acc[1][1] = MFMA_I8(ha1, hb1, acc[1][1], 0, 0, 0);
        fa0 = na0; fa1 = na1; fb0 = nb0; fb1 = nb1;
        ha0 = ma0; ha1 = ma1; hb0 = mb0; hb1 = mb1;
        pa0 += 2048; pa1 += 2048; pb0 += 2048; pb1 += 2048;
    }
    acc[0][0] = MFMA_I8(fa0, fb0, acc[0][0], 0, 0, 0);
    acc[0][1] = MFMA_I8(fa0, fb1, acc[0][1], 0, 0, 0);
    acc[1][0] = MFMA_I8(fa1, fb0, acc[1][0], 0, 0, 0);
    acc[1][1] = MFMA_I8(fa1, fb1, acc[1][1], 0, 0, 0);
    acc[0][0] = MFMA_I8(ha0, hb0, acc[0][0], 0, 0, 0);
    acc[0][1] = MFMA_I8(ha0, hb1, acc[0][1], 0, 0, 0);
    acc[1][0] = MFMA_I8(ha1, hb0, acc[1][0], 0, 0, 0);
    acc[1][1] = MFMA_I8(ha1, hb1, acc[1][1], 0, 0, 0);

    float sb[2];
    #pragma unroll
    for (int ni = 0; ni < 2; ++ni) sb[ni] = sB[n0 + wn + ni * 32 + cl];
    #pragma unroll
    for (int mi = 0; mi < 2; ++mi) {
        #pragma unroll
        for (int reg = 0; reg < 16; ++reg) {
            long m = m0 + wm + mi * 32 + (reg & 3) + 8 * (reg >> 2) + 4 * kq;
            float sa = sA[m];
            #pragma unroll
            for (int ni = 0; ni < 2; ++ni) {
                long n = n0 + wn + ni * 32 + cl;
                O[m * N + n] = (float)acc[mi][ni][reg] * sa * sb[ni];
            }
        }
    }
}

// ---------------------------------------------------------------------------

extern "C" void kernel_launch(void* const* d_in, const int* in_sizes, int n_in,
                              void* d_out, int out_size, void* d_ws, size_t ws_size,
                              hipStream_t stream)
{
    const float* x  = (const float*)d_in[0];   // [4,2048,2048]
    const float* Wg = (const float*)d_in[1];   // [5632,2048]
    const float* Wu = (const float*)d_in[2];   // [5632,2048]
    const float* Wd = (const float*)d_in[3];   // [2048,5632]
    float* out = (float*)d_out;                // [4,2048,2048] fp32

    const int M  = 8192;      // B*S
    const int H  = 2048;
    const int I  = 5632;

    // ---- fixed workspace regions (~49.1 MiB) ----
    char* p = (char*)d_ws;
    int8_t* xq  = (int8_t*)p; p += (size_t)M * H;
    float*  sx  = (float*)p;  p += (size_t)M * 4;
    int8_t* wgq = (int8_t*)p; p += (size_t)I * H;
    float*  swg = (float*)p;  p += (size_t)I * 4;
    int8_t* wuq = (int8_t*)p; p += (size_t)I * H;
    float*  swu = (float*)p;  p += (size_t)I * 4;
    int8_t* wdq = (int8_t*)p; p += (size_t)H * I;
    float*  swd = (float*)p;  p += (size_t)H * 4;
    float*  sh  = (float*)p;  p += (size_t)M * 4;
    const size_t fixed_bytes = (size_t)(p - (char*)d_ws);

    // ---- largest M-chunk whose h (fp32) + hq (int8) fit ws_size ----
    int Mc = 256;
    for (int cand = 8192; cand >= 256; cand >>= 1) {
        size_t need = fixed_bytes + (size_t)cand * I * 5;
        if (need <= ws_size) { Mc = cand; break; }
    }
    float*  hbuf = (float*)p;  p += (size_t)Mc * I * 4;
    int8_t* hq   = (int8_t*)p;

    // 1) quantize weights (qmax=7) and activations (qmax=127) into flat layout
    quant_rows_shuf<<<I, 256, 0, stream>>>(Wg, wgq, swg, H / 4, 7.f);
    quant_rows_shuf<<<I, 256, 0, stream>>>(Wu, wuq, swu, H / 4, 7.f);
    quant_rows_shuf<<<H, 256, 0, stream>>>(Wd, wdq, swd, I / 4, 7.f);
    quant_rows_shuf<<<M, 256, 0, stream>>>(x,  xq,  sx,  H / 4, 127.f);

    // 2) per M-chunk: gate+up GEMM + SwiGLU -> h ; quantize h ; down-proj
    for (int m0 = 0; m0 < M; m0 += Mc) {
        gemm_dual_flat<<<dim3(I / 128, Mc / 128), 256, 0, stream>>>(
            xq + (size_t)m0 * H, sx + m0, wgq, swg, wuq, swu,
            hbuf, Mc, I, H);
        quant_rows_shuf<<<Mc, 256, 0, stream>>>(hbuf, hq, sh + m0, I / 4, 127.f);
        gemm_single_flat<<<dim3(H / 128, Mc / 128), 256, 0, stream>>>(
            hq, sh + m0, wdq, swd, out + (size_t)m0 * H, Mc, H, I);
    }
}